// Round 9
// baseline (2331.661 us; speedup 1.0000x reference)
//
#include <hip/hip_runtime.h>

#define N_NODES 100000
#define N_EDGES 1600000

#define BKT_SHIFT 8
#define BKT_NODES 256
#define NBK ((N_NODES + BKT_NODES - 1) / BKT_NODES)      // 391 buckets
#define CHUNK 4096
#define NCHUNKS ((N_EDGES + CHUNK - 1) / CHUNK)          // 391 chunks
#define BCAP 6144
#define NR 13                                            // src ranges of 8192 nodes (2 MB)
#define NKEY (NR * 8)                                    // 104 sort bins: key = range*8 + oct
#define SEG_STRIDE (NKEY + 1)

// ---------------- bucket-level histogram (391 bins) ----------------
__global__ __launch_bounds__(512) void bhist_kernel(const int* __restrict__ dst,
                                                    int* __restrict__ bhist) {
    __shared__ int h[NBK];
    for (int i = threadIdx.x; i < NBK; i += 512) h[i] = 0;
    __syncthreads();
    int stride = gridDim.x * 512;
    for (int e = blockIdx.x * 512 + threadIdx.x; e < N_EDGES; e += stride)
        atomicAdd(&h[dst[e] >> BKT_SHIFT], 1);
    __syncthreads();
    for (int i = threadIdx.x; i < NBK; i += 512) {
        int v = h[i];
        if (v) atomicAdd(&bhist[i], v);
    }
}

// ---------------- single-block scan of bucket histogram ----------------
__global__ __launch_bounds__(512) void scan_bhist_kernel(const int* __restrict__ bhist,
                                                         int* __restrict__ bbase,
                                                         int* __restrict__ bcursor) {
    __shared__ int s[512];
    int t = threadIdx.x;
    int v = (t < NBK) ? bhist[t] : 0;
    s[t] = v;
    __syncthreads();
    for (int off = 1; off < 512; off <<= 1) {
        int u = (t >= off) ? s[t - off] : 0;
        __syncthreads();
        s[t] += u;
        __syncthreads();
    }
    if (t < NBK) {
        int excl = s[t] - v;
        bbase[t] = excl;
        bcursor[t] = excl;
    }
    if (t == 0) bbase[NBK] = N_EDGES;
}

// ---------------- phase A: bin edges by 256-node dst bucket ----------------
__global__ __launch_bounds__(512) void binA_kernel(const int* __restrict__ src,
                                                   const int* __restrict__ dst,
                                                   int* __restrict__ bcursor,
                                                   int2* __restrict__ csr_tmp) {
    __shared__ int2 staged[CHUNK];   // 32 KB
    __shared__ int delta[CHUNK];     // 16 KB
    __shared__ int hist[NBK];
    __shared__ int lcur[NBK];
    __shared__ int gdel[NBK];
    __shared__ int scan_s[512];
    int t = threadIdx.x;
    int e0 = blockIdx.x * CHUNK;
    int n = N_EDGES - e0; if (n > CHUNK) n = CHUNK;

    for (int i = t; i < NBK; i += 512) hist[i] = 0;
    __syncthreads();
    for (int i = t; i < n; i += 512) atomicAdd(&hist[dst[e0 + i] >> BKT_SHIFT], 1);
    __syncthreads();
    int v = (t < NBK) ? hist[t] : 0;
    scan_s[t] = v;
    __syncthreads();
    for (int off = 1; off < 512; off <<= 1) {
        int u = (t >= off) ? scan_s[t - off] : 0;
        __syncthreads();
        scan_s[t] += u;
        __syncthreads();
    }
    if (t < NBK) {
        int excl = scan_s[t] - v;
        lcur[t] = excl;
        int g = atomicAdd(&bcursor[t], v);
        gdel[t] = g - excl;
    }
    __syncthreads();
    for (int i = t; i < n; i += 512) {
        int s = src[e0 + i];
        int d = dst[e0 + i];
        int bkt = d >> BKT_SHIFT;
        int slot = atomicAdd(&lcur[bkt], 1);
        staged[slot] = make_int2(s, d);
        delta[slot] = gdel[bkt];
    }
    __syncthreads();
    for (int p = t; p < n; p += 512) csr_tmp[delta[p] + p] = staged[p];
}

// ---------------- phase B: per-bucket (range,oct) counting sort + dinv + segs ----------------
// csr entry: packed u32 = src | (dloc << 17)
__global__ __launch_bounds__(256) void binB_kernel(const int* __restrict__ bbase,
                                                   const int2* __restrict__ csr_tmp,
                                                   int* __restrict__ segs,
                                                   float* __restrict__ dinv,
                                                   unsigned int* __restrict__ csr) {
    __shared__ unsigned int stag[BCAP];     // 24 KB
    __shared__ unsigned char key_s[BCAP];   // 6 KB
    __shared__ unsigned int out_s[BCAP];    // 24 KB
    __shared__ int lcnt[BKT_NODES];
    __shared__ int khist[NKEY];
    __shared__ int kcur[NKEY];
    __shared__ int ss[256];
    int t = threadIdx.x;
    int bucket = blockIdx.x;
    int node0 = bucket * BKT_NODES;
    int base = bbase[bucket];
    int cnt = bbase[bucket + 1] - base;
    lcnt[t] = 0;
    if (t < NKEY) khist[t] = 0;
    __syncthreads();
    bool fits = (cnt <= BCAP);
    if (fits) {
        for (int i = t; i < cnt; i += 256) {
            int2 e = csr_tmp[base + i];
            int dl = e.y - node0;
            int key = (e.x >> 13) * 8 + (dl >> 5);
            stag[i] = (unsigned int)e.x | ((unsigned int)dl << 17);
            key_s[i] = (unsigned char)key;
            atomicAdd(&lcnt[dl], 1);
            atomicAdd(&khist[key], 1);
        }
    } else {
        for (int i = t; i < cnt; i += 256) {
            int2 e = csr_tmp[base + i];
            int dl = e.y - node0;
            atomicAdd(&lcnt[dl], 1);
            atomicAdd(&khist[(e.x >> 13) * 8 + (dl >> 5)], 1);
        }
    }
    __syncthreads();
    // exclusive scan of khist (NKEY=104) via 256-wide Hillis
    int v = (t < NKEY) ? khist[t] : 0;
    ss[t] = v;
    __syncthreads();
    for (int off = 1; off < 256; off <<= 1) {
        int u = (t >= off) ? ss[t - off] : 0;
        __syncthreads();
        ss[t] += u;
        __syncthreads();
    }
    if (t < NKEY) {
        int excl = ss[t] - v;
        kcur[t] = excl;
        segs[bucket * SEG_STRIDE + t] = base + excl;
    }
    if (t == 0) segs[bucket * SEG_STRIDE + NKEY] = base + cnt;
    int node = node0 + t;
    if (node < N_NODES) dinv[node] = rsqrtf((float)lcnt[t] + 1.0f);
    __syncthreads();
    if (fits) {
        for (int i = t; i < cnt; i += 256) {
            int slot = atomicAdd(&kcur[key_s[i]], 1);
            out_s[slot] = stag[i];
        }
        __syncthreads();
        for (int i = t; i < cnt; i += 256) csr[base + i] = out_s[i];
    } else {
        // statistically unreachable, correct fallback (scattered writes)
        for (int i = t; i < cnt; i += 256) {
            int2 e = csr_tmp[base + i];
            int dl = e.y - node0;
            int key = (e.x >> 13) * 8 + (dl >> 5);
            int slot = atomicAdd(&kcur[key], 1);
            csr[base + slot] = (unsigned int)e.x | ((unsigned int)dl << 17);
        }
    }
}

// ---------------- prescale: Xs = X * dinv (row-wise, plain [n][64] layout) ----------------
__global__ __launch_bounds__(256) void prescale_kernel(const float* __restrict__ X,
                                                       const float* __restrict__ dinv,
                                                       float* __restrict__ Xs) {
    int i = blockIdx.x * 256 + threadIdx.x;  // float4 index
    if (i < N_NODES * 16) {
        float4 v = ((const float4*)X)[i];
        float d = dinv[i >> 4];
        ((float4*)Xs)[i] = make_float4(v.x * d, v.y * d, v.z * d, v.w * d);
    }
}

// ---------------- range-phased LDS-accumulator gather + fused matvec epilogue ----------------
// Block = half-bucket (128 dst nodes, 32 KB accum). Waves own dst-octs; all blocks
// sweep src ranges 0..NR-1 in order => chip-wide L2 phase locality on 2 MB slices.
__global__ __launch_bounds__(256) void gather_kernel(
    const float* __restrict__ Xs, const float* __restrict__ dinv,
    const unsigned int* __restrict__ csr, const int* __restrict__ segs,
    const float* __restrict__ W, const float* __restrict__ b,
    float* __restrict__ out, int mode) {
    __shared__ float accum[128 * 64];  // 32 KB
    int t = threadIdx.x;
    int lane = t & 63;
    int wave = t >> 6;        // 0..3
    int sub = lane >> 4;      // 0..3: edge slot
    int l16 = lane & 15;      // float4 channel group
    int bucket = blockIdx.x >> 1;
    int half = blockIdx.x & 1;
    int node0 = bucket * BKT_NODES + half * 128;
    int nvalid = N_NODES - node0; if (nvalid > 128) nvalid = 128;
    const float4* Xv = (const float4*)Xs;

    // init accum with self (pre-scaled) rows
    float4* accv = (float4*)accum;
    for (int i = t; i < nvalid * 16; i += 256) accv[i] = Xv[(size_t)node0 * 16 + i];
    __syncthreads();

    const int segbase = bucket * SEG_STRIDE;
    int oct = half * 4 + wave;
    for (int r = 0; r < NR; r++) {
        int k = r * 8 + oct;
        int s0 = segs[segbase + k];
        int s1 = segs[segbase + k + 1];
        if (s0 >= s1) continue;
        int niter = (s1 - s0 + 3) >> 2;
        int i = s0 + sub;
        unsigned int eA = (i < s1) ? csr[i] : 0u;
        unsigned int eB = (i + 4 < s1) ? csr[i + 4] : 0u;
        float4 rA = Xv[(size_t)(eA & 0x1FFFF) * 16 + l16];
        for (int it = 0; it < niter; it++) {
            float m = (i < s1) ? 1.0f : 0.0f;
            int dl = (int)((eA >> 17) & 127);
            unsigned int eC = (i + 8 < s1) ? csr[i + 8] : 0u;
            float4 rB = Xv[(size_t)(eB & 0x1FFFF) * 16 + l16];
            float* dp = &accum[dl * 64 + l16 * 4];
            unsafeAtomicAdd(dp + 0, rA.x * m);
            unsafeAtomicAdd(dp + 1, rA.y * m);
            unsafeAtomicAdd(dp + 2, rA.z * m);
            unsafeAtomicAdd(dp + 3, rA.w * m);
            eA = eB; eB = eC; rA = rB; i += 4;
        }
    }
    __syncthreads();

    // epilogue: wave w handles nodes [w*32, w*32+32)
    for (int j = 0; j < 32; j++) {
        int rel = wave * 32 + j;
        if (rel >= nvalid) break;
        int nn = node0 + rel;
        float di = dinv[nn];
        float a = accum[rel * 64 + lane] * di;
        int ai = __float_as_int(a);
        float r = b[lane];
#pragma unroll
        for (int kk = 0; kk < 64; kk++) {
            r = fmaf(__int_as_float(__builtin_amdgcn_readlane(ai, kk)), W[kk * 64 + lane], r);
        }
        if (mode) r *= di;
        out[(size_t)nn * 64 + lane] = r;
    }
}

extern "C" void kernel_launch(void* const* d_in, const int* in_sizes, int n_in,
                              void* d_out, int out_size, void* d_ws, size_t ws_size,
                              hipStream_t stream) {
    const float* emb = (const float*)d_in[0];
    const int* edge  = (const int*)d_in[1];
    const float* W1 = (const float*)d_in[2];
    const float* b1 = (const float*)d_in[3];
    const float* W2 = (const float*)d_in[4];
    const float* b2 = (const float*)d_in[5];
    const float* W3 = (const float*)d_in[6];
    const float* b3 = (const float*)d_in[7];
    float* out = (float*)d_out;

    const int* src = edge;
    const int* dst = edge + N_EDGES;

    char* ws = (char*)d_ws;
    size_t off = 0;
    int* bhist = (int*)(ws + off);          off += 2048;
    int* bbase = (int*)(ws + off);          off += 2048;     // NBK+1
    int* bcursor = (int*)(ws + off);        off += 2048;
    int* segs = (int*)(ws + off);           off += 167040;   // NBK * 105 ints
    float* dinv = (float*)(ws + off);       off += 400128;
    unsigned int* csr = (unsigned int*)(ws + off); off += 6400128;
    int2* csr_tmp = (int2*)(ws + off);      off += 12800128;
    float* Xa = (float*)(ws + off);         off += 25600000;
    float* Xb = (float*)(ws + off);         // 25.6 MB

    // ---- CSR build (shared by all 3 layers) ----
    hipMemsetAsync(bhist, 0, NBK * sizeof(int), stream);
    bhist_kernel<<<64, 512, 0, stream>>>(dst, bhist);
    scan_bhist_kernel<<<1, 512, 0, stream>>>(bhist, bbase, bcursor);
    binA_kernel<<<NCHUNKS, 512, 0, stream>>>(src, dst, bcursor, csr_tmp);
    binB_kernel<<<NBK, 256, 0, stream>>>(bbase, csr_tmp, segs, dinv, csr);

    // Xs0 = emb * dinv
    prescale_kernel<<<(N_NODES * 16 + 255) / 256, 256, 0, stream>>>(emb, dinv, Xa);

    const int GBLOCKS = NBK * 2;  // 782 half-bucket blocks

    gather_kernel<<<GBLOCKS, 256, 0, stream>>>(Xa, dinv, csr, segs, W1, b1, Xb, 1);
    gather_kernel<<<GBLOCKS, 256, 0, stream>>>(Xb, dinv, csr, segs, W2, b2, Xa, 1);
    gather_kernel<<<GBLOCKS, 256, 0, stream>>>(Xa, dinv, csr, segs, W3, b3, out, 0);
}

// Round 10
// 2180.916 us; speedup vs baseline: 1.0691x; 1.0691x over previous
//
#include <hip/hip_runtime.h>

#define N_NODES 100000
#define N_EDGES 1600000

#define HB_NODES 128
#define NBH ((N_NODES + HB_NODES - 1) / HB_NODES)        // 782 half-buckets
#define CHUNK 4096
#define NCHUNKS ((N_EDGES + CHUNK - 1) / CHUNK)          // 391 chunks
#define ACC_STRIDE 65                                    // bank-swizzle stride (floats)

// ---------------- half-bucket histogram (782 bins) ----------------
__global__ __launch_bounds__(512) void bhist_kernel(const int* __restrict__ dst,
                                                    int* __restrict__ bhist) {
    __shared__ int h[NBH];
    for (int i = threadIdx.x; i < NBH; i += 512) h[i] = 0;
    __syncthreads();
    int stride = gridDim.x * 512;
    const int4* d4 = (const int4*)dst;
    for (int e = blockIdx.x * 512 + threadIdx.x; e < N_EDGES / 4; e += stride) {
        int4 v = d4[e];
        atomicAdd(&h[v.x >> 7], 1);
        atomicAdd(&h[v.y >> 7], 1);
        atomicAdd(&h[v.z >> 7], 1);
        atomicAdd(&h[v.w >> 7], 1);
    }
    __syncthreads();
    for (int i = threadIdx.x; i < NBH; i += 512) {
        int v = h[i];
        if (v) atomicAdd(&bhist[i], v);
    }
}

// ---------------- single-block exclusive scan (pair trick, 782 bins) ----------------
__global__ __launch_bounds__(512) void scan_bhist_kernel(const int* __restrict__ bhist,
                                                         int* __restrict__ bbase,
                                                         int* __restrict__ bcursor) {
    __shared__ int ss[512];
    int t = threadIdx.x;
    int h0 = (2 * t < NBH) ? bhist[2 * t] : 0;
    int h1 = (2 * t + 1 < NBH) ? bhist[2 * t + 1] : 0;
    ss[t] = h0 + h1;
    __syncthreads();
    for (int off = 1; off < 512; off <<= 1) {
        int u = (t >= off) ? ss[t - off] : 0;
        __syncthreads();
        ss[t] += u;
        __syncthreads();
    }
    int pexcl = ss[t] - (h0 + h1);
    if (2 * t < NBH) { bbase[2 * t] = pexcl; bcursor[2 * t] = pexcl; }
    if (2 * t + 1 < NBH) { bbase[2 * t + 1] = pexcl + h0; bcursor[2 * t + 1] = pexcl + h0; }
    if (t == 0) bbase[NBH] = N_EDGES;
}

// ---------------- binA: bin edges by half-bucket; entry = src | dloc<<17 ----------------
__global__ __launch_bounds__(512) void binA_kernel(const int* __restrict__ src,
                                                   const int* __restrict__ dst,
                                                   int* __restrict__ bcursor,
                                                   unsigned int* __restrict__ csr) {
    __shared__ unsigned int staged[CHUNK];   // 16 KB
    __shared__ int delta[CHUNK];             // 16 KB
    __shared__ int hist[NBH];                // 3.1 KB
    __shared__ int lcur[NBH];
    __shared__ int gdel[NBH];
    __shared__ int ss[512];
    int t = threadIdx.x;
    int e0 = blockIdx.x * CHUNK;
    int n = N_EDGES - e0; if (n > CHUNK) n = CHUNK;

    for (int i = t; i < NBH; i += 512) hist[i] = 0;
    __syncthreads();
    for (int i = t; i < n; i += 512) atomicAdd(&hist[dst[e0 + i] >> 7], 1);
    __syncthreads();
    // pair-trick exclusive scan of 782 bins
    int h0 = (2 * t < NBH) ? hist[2 * t] : 0;
    int h1 = (2 * t + 1 < NBH) ? hist[2 * t + 1] : 0;
    ss[t] = h0 + h1;
    __syncthreads();
    for (int off = 1; off < 512; off <<= 1) {
        int u = (t >= off) ? ss[t - off] : 0;
        __syncthreads();
        ss[t] += u;
        __syncthreads();
    }
    int pexcl = ss[t] - (h0 + h1);
    if (2 * t < NBH) lcur[2 * t] = pexcl;
    if (2 * t + 1 < NBH) lcur[2 * t + 1] = pexcl + h0;
    __syncthreads();
    for (int i = t; i < NBH; i += 512) {
        int v = hist[i];
        int g = v ? atomicAdd(&bcursor[i], v) : 0;
        gdel[i] = g - lcur[i];
    }
    __syncthreads();
    for (int i = t; i < n; i += 512) {
        int s = src[e0 + i];
        int d = dst[e0 + i];
        int bin = d >> 7;
        int slot = atomicAdd(&lcur[bin], 1);
        staged[slot] = (unsigned int)s | ((unsigned int)(d & 127) << 17);
        delta[slot] = gdel[bin];
    }
    __syncthreads();
    for (int p = t; p < n; p += 512) csr[delta[p] + p] = staged[p];
}

// ---------------- degB: per-half-bucket degree -> dinv ----------------
__global__ __launch_bounds__(128) void degB_kernel(const int* __restrict__ bbase,
                                                   const unsigned int* __restrict__ csr,
                                                   float* __restrict__ dinv) {
    __shared__ int lcnt[HB_NODES];
    int t = threadIdx.x;
    int hb = blockIdx.x;
    int base = bbase[hb];
    int cnt = bbase[hb + 1] - base;
    lcnt[t] = 0;
    __syncthreads();
    for (int i = t; i < cnt; i += 128) atomicAdd(&lcnt[(csr[base + i] >> 17) & 127], 1);
    __syncthreads();
    int node = hb * HB_NODES + t;
    if (node < N_NODES) dinv[node] = rsqrtf((float)lcnt[t] + 1.0f);
}

// ---------------- prescale: Xs = X * dinv ----------------
__global__ __launch_bounds__(256) void prescale_kernel(const float* __restrict__ X,
                                                       const float* __restrict__ dinv,
                                                       float* __restrict__ Xs) {
    int i = blockIdx.x * 256 + threadIdx.x;  // float4 index
    if (i < N_NODES * 16) {
        float4 v = ((const float4*)X)[i];
        float d = dinv[i >> 4];
        ((float4*)Xs)[i] = make_float4(v.x * d, v.y * d, v.z * d, v.w * d);
    }
}

// ---------------- LDS-accumulator gather + fused matvec epilogue ----------------
// Block = half-bucket (128 dst nodes). accum layout (bank-swizzled):
//   channel ch of node rel lives at accum[rel*65 + (ch&3)*16 + (ch>>2)]
// Edge loop: 16 lanes x float4 per row, 4 edges per instr, depth-2 prefetch,
// fire-and-forget ds_add_f32 into accum.
__global__ __launch_bounds__(512) void gather_kernel(
    const float* __restrict__ Xs, const float* __restrict__ dinv,
    const unsigned int* __restrict__ csr, const int* __restrict__ bbase,
    const float* __restrict__ W, const float* __restrict__ b,
    float* __restrict__ out, int mode) {
    __shared__ float accum[HB_NODES * ACC_STRIDE];  // 33.3 KB
    int t = threadIdx.x;
    int lane = t & 63;
    int wave = t >> 6;        // 0..7
    int sub = lane >> 4;      // 0..3: edge slot
    int l16 = lane & 15;      // float4 channel group
    int hb = blockIdx.x;
    int node0 = hb * HB_NODES;
    int nvalid = N_NODES - node0; if (nvalid > HB_NODES) nvalid = HB_NODES;
    const float4* Xv = (const float4*)Xs;

    // init accum with self (pre-scaled) rows, swizzled
    for (int i = t; i < nvalid * 64; i += 512) {
        int rel = i >> 6, ch = i & 63;
        accum[rel * ACC_STRIDE + (ch & 3) * 16 + (ch >> 2)] = Xs[(size_t)(node0 + rel) * 64 + ch];
    }
    __syncthreads();

    int s0 = bbase[hb], s1 = bbase[hb + 1];
    int cnt = s1 - s0;
    int per4 = (cnt + 31) >> 5;               // 4-edge groups per wave
    int start = s0 + wave * per4 * 4;
    int iend = start + per4 * 4; if (iend > s1) iend = s1;
    if (start < iend) {
        int iA = start + sub;
        unsigned int eA = (iA < iend) ? csr[iA] : 0u;
        unsigned int eB = (iA + 4 < iend) ? csr[iA + 4] : 0u;
        float4 rA = Xv[(size_t)(eA & 0x1FFFF) * 16 + l16];
        for (int ib = start; ib < iend; ib += 4) {
            int idx = ib + sub;
            unsigned int eC = (idx + 8 < iend) ? csr[idx + 8] : 0u;
            float4 rB = Xv[(size_t)(eB & 0x1FFFF) * 16 + l16];
            float m = (idx < iend) ? 1.0f : 0.0f;
            int dl = (int)((eA >> 17) & 127);
            float* dp = &accum[dl * ACC_STRIDE + l16];
            atomicAdd(dp + 0,  rA.x * m);
            atomicAdd(dp + 16, rA.y * m);
            atomicAdd(dp + 32, rA.z * m);
            atomicAdd(dp + 48, rA.w * m);
            eA = eB; eB = eC; rA = rB;
        }
    }
    __syncthreads();

    // epilogue: wave w handles nodes [w*16, w*16+16)
    float wcol[64];
#pragma unroll
    for (int k = 0; k < 64; k++) wcol[k] = W[k * 64 + lane];
    float blane = b[lane];
    for (int j = 0; j < 16; j++) {
        int rel = wave * 16 + j;
        if (rel >= nvalid) break;
        int nn = node0 + rel;
        float di = dinv[nn];
        float a = accum[rel * ACC_STRIDE + (lane & 3) * 16 + (lane >> 2)] * di;
        int ai = __float_as_int(a);
        float r = blane;
#pragma unroll
        for (int kk = 0; kk < 64; kk++) {
            r = fmaf(__int_as_float(__builtin_amdgcn_readlane(ai, kk)), wcol[kk], r);
        }
        if (mode) r *= di;
        out[(size_t)nn * 64 + lane] = r;
    }
}

extern "C" void kernel_launch(void* const* d_in, const int* in_sizes, int n_in,
                              void* d_out, int out_size, void* d_ws, size_t ws_size,
                              hipStream_t stream) {
    const float* emb = (const float*)d_in[0];
    const int* edge  = (const int*)d_in[1];
    const float* W1 = (const float*)d_in[2];
    const float* b1 = (const float*)d_in[3];
    const float* W2 = (const float*)d_in[4];
    const float* b2 = (const float*)d_in[5];
    const float* W3 = (const float*)d_in[6];
    const float* b3 = (const float*)d_in[7];
    float* out = (float*)d_out;

    const int* src = edge;
    const int* dst = edge + N_EDGES;

    char* ws = (char*)d_ws;
    size_t off = 0;
    int* bhist = (int*)(ws + off);      off += 4096;
    int* bbase = (int*)(ws + off);      off += 4096;     // NBH+1
    int* bcursor = (int*)(ws + off);    off += 4096;
    float* dinv = (float*)(ws + off);   off += 400128;
    unsigned int* csr = (unsigned int*)(ws + off); off += 6400128;
    float* Xa = (float*)(ws + off);     off += 25600000;
    float* Xb = (float*)(ws + off);     // 25.6 MB

    // ---- build (shared by all 3 layers) ----
    hipMemsetAsync(bhist, 0, NBH * sizeof(int), stream);
    bhist_kernel<<<128, 512, 0, stream>>>(dst, bhist);
    scan_bhist_kernel<<<1, 512, 0, stream>>>(bhist, bbase, bcursor);
    binA_kernel<<<NCHUNKS, 512, 0, stream>>>(src, dst, bcursor, csr);
    degB_kernel<<<NBH, 128, 0, stream>>>(bbase, csr, dinv);

    // Xs0 = emb * dinv
    prescale_kernel<<<(N_NODES * 16 + 255) / 256, 256, 0, stream>>>(emb, dinv, Xa);

    gather_kernel<<<NBH, 512, 0, stream>>>(Xa, dinv, csr, bbase, W1, b1, Xb, 1);
    gather_kernel<<<NBH, 512, 0, stream>>>(Xb, dinv, csr, bbase, W2, b2, Xa, 1);
    gather_kernel<<<NBH, 512, 0, stream>>>(Xa, dinv, csr, bbase, W3, b3, out, 0);
}